// Round 5
// baseline (204.334 us; speedup 1.0000x reference)
//
#include <hip/hip_runtime.h>
#include <stdint.h>

// YOLO loss, B=16384, 7x7 grid, pred=30ch f32, targ=25ch f32 -> scalar sum.
//
// Round-3 diagnosis: stage -> __syncthreads per tile = vmcnt(0) drain per tile
// (m97 barrier-drain stall) -> ~900 cyc exposed latency per tile, only 1.6
// waves/SIMD to hide it -> 67 us with both pipes <17% busy.
//
// Fix: SINGLE-WAVE blocks (no __syncthreads anywhere) + 2-deep double-buffered
// global_load_lds pipeline with exact counted vmcnt waits (T3/T4 pattern):
//   issue stage(j+1) [15 ticks] -> s_waitcnt vmcnt(15) -> compute tile j.
// Prefetched loads stay in flight across compute; never drain to 0 in-loop.
// 4 distinct __shared__ objects so alias analysis can't force extra waits.
//
// (Round 4 was an infra failure -- container died before running; resubmit.)

#define TPB    64
#define KT     7                  // tiles per block
#define GRID   1792               // 1792 * 7 * 64 = 802816 cells
#define P_F4   480                // float4 per pred tile (64 cells * 30 / 4)
#define T_F4   400                // float4 per targ tile (64 cells * 25 / 4)

// global_load_lds width=16: LDS dest is wave-uniform base + lane*16 (linear).
#define GL2LDS(gptr, lptr)                                                    \
    __builtin_amdgcn_global_load_lds(                                         \
        (const __attribute__((address_space(1))) void*)(gptr),                \
        (__attribute__((address_space(3))) void*)(uintptr_t)(lptr), 16, 0, 0)

__global__ __launch_bounds__(TPB) void yolo_loss_kernel(
    const float* __restrict__ pred,
    const float* __restrict__ targ,
    float* __restrict__ out)
{
    // two independent buffers (distinct objects -> provable no-alias)
    __shared__ float4 spA[P_F4], stA[T_F4];   // 7680 B + 6400 B
    __shared__ float4 spB[P_F4], stB[T_F4];   // x2 = 28160 B total

    const int tid = threadIdx.x;

    // ---- stage one 64-cell tile: exactly 15 vmcnt ticks ----
    auto STAGE = [&](int t, float4* sp4, float4* st4) {
        const float4* gp = (const float4*)pred + (size_t)t * P_F4;
        const float4* gt = (const float4*)targ + (size_t)t * T_F4;
        #pragma unroll
        for (int r = 0; r < 7; ++r) GL2LDS(gp + tid + r * 64, sp4 + tid + r * 64);
        if (tid < 32)               GL2LDS(gp + 448 + tid,    sp4 + 448 + tid);   // 8
        #pragma unroll
        for (int r = 0; r < 6; ++r) GL2LDS(gt + tid + r * 64, st4 + tid + r * 64);
        if (tid < 16)               GL2LDS(gt + 384 + tid,    st4 + 384 + tid);   // +7
    };

    // ---- per-cell loss from a staged tile (thread tid owns cell tid) ----
    auto CELL = [&](const float* sp, const float* st) -> float {
        const float2* pv2 = (const float2*)(sp + tid * 30);  // byte 120*tid, 8B-aligned
        float pv[30];
        #pragma unroll
        for (int i = 0; i < 15; ++i) {
            float2 v = pv2[i];
            pv[2*i] = v.x; pv[2*i+1] = v.y;
        }
        const float* tvp = st + tid * 25;
        float tv[25];
        #pragma unroll
        for (int i = 0; i < 25; ++i) tv[i] = tvp[i];

        float c1 = pv[4], c2 = pv[9], cc = tv[4];
        bool present = (cc == 1.0f);
        bool resp1   = (c1 > c2);

        float d1 = c1 - cc, d2 = c2 - cc;
        float obj = present ? (resp1 ? d1 * d1 : d2 * d2)
                            : 0.5f * (c1 * c1 + c2 * c2);

        float cls = 0.0f;
        #pragma unroll
        for (int k = 0; k < 20; ++k) {
            float d = pv[10 + k] - tv[5 + k];
            cls += d * d;
        }

        float pc0 = resp1 ? pv[0] : pv[5];
        float pc1 = resp1 ? pv[1] : pv[6];
        float ph0 = resp1 ? pv[2] : pv[7];
        float ph1 = resp1 ? pv[3] : pv[8];
        float b0 = pc0 - tv[0];
        float b1 = pc1 - tv[1];
        float s0 = sqrtf(ph0) - sqrtf(tv[2]);
        float s1 = sqrtf(ph1) - sqrtf(tv[3]);
        float box = b0 * b0 + b1 * b1 + s0 * s0 + s1 * s1;

        return obj + (present ? (cls + 5.0f * box) : 0.0f);
    };

    const int base = blockIdx.x * KT;
    float loss = 0.0f;

    STAGE(base, spA, stA);                       // prologue: 15 in flight

    #pragma unroll
    for (int j = 0; j < KT; ++j) {
        const bool odd = (j & 1);
        if (j + 1 < KT) {
            // prefetch tile j+1 into the other buffer: +15 -> 30 in flight
            if (odd) STAGE(base + j + 1, spA, stA);
            else     STAGE(base + j + 1, spB, stB);
            // wait only for tile j's 15 loads; the new 15 stay in flight
            asm volatile("s_waitcnt vmcnt(15)" ::: "memory");
        } else {
            asm volatile("s_waitcnt vmcnt(0)" ::: "memory");
        }
        __builtin_amdgcn_sched_barrier(0);       // rule #18: pin the wait

        loss += odd ? CELL((const float*)spB, (const float*)stB)
                    : CELL((const float*)spA, (const float*)stA);
    }

    // ---- wave-64 reduce -> one atomic per block (no LDS, no barrier) ----
    #pragma unroll
    for (int off = 32; off > 0; off >>= 1)
        loss += __shfl_down(loss, off);
    if (tid == 0)
        atomicAdd(out, loss);
}

extern "C" void kernel_launch(void* const* d_in, const int* in_sizes, int n_in,
                              void* d_out, int out_size, void* d_ws, size_t ws_size,
                              hipStream_t stream)
{
    const float* pred = (const float*)d_in[0];
    const float* targ = (const float*)d_in[1];
    float* out = (float*)d_out;

    // harness poisons d_out with 0xAA before every launch -> zero it (capture-safe)
    hipMemsetAsync(out, 0, sizeof(float), stream);

    hipLaunchKernelGGL(yolo_loss_kernel, dim3(GRID), dim3(TPB), 0, stream,
                       pred, targ, out);
}